// Round 1
// baseline (211.643 us; speedup 1.0000x reference)
//
#include <hip/hip_runtime.h>
#include <hip/hip_bf16.h>

#define H 8
#define D 32
#define HD 256            // H*D floats per edge/node row
#define NEG_SLOPE 0.01f

// ---------------- CSR build ----------------

__global__ void hist_kernel(const int* __restrict__ dst, int E, int* __restrict__ count) {
    int i = blockIdx.x * blockDim.x + threadIdx.x;
    if (i < E) atomicAdd(&count[dst[i]], 1);
}

// per-256-block exclusive scan; writes block totals
__global__ void scan_block_kernel(const int* __restrict__ in, int n,
                                  int* __restrict__ out_excl, int* __restrict__ bsum) {
    __shared__ int s[256];
    int t = threadIdx.x;
    int i = blockIdx.x * 256 + t;
    int v = (i < n) ? in[i] : 0;
    s[t] = v;
    __syncthreads();
    for (int off = 1; off < 256; off <<= 1) {
        int x = (t >= off) ? s[t - off] : 0;
        __syncthreads();
        s[t] += x;
        __syncthreads();
    }
    if (i < n) out_excl[i] = s[t] - v;            // exclusive
    if (t == 255) bsum[blockIdx.x] = s[255];      // block total
}

// single-block exclusive scan of up to 1024 block totals (NB = ceil(100k/256) = 391)
__global__ void scan_single_kernel(int* __restrict__ data, int n) {
    __shared__ int s[1024];
    int t = threadIdx.x;
    int v = (t < n) ? data[t] : 0;
    s[t] = v;
    __syncthreads();
    for (int off = 1; off < 1024; off <<= 1) {
        int x = (t >= off) ? s[t - off] : 0;
        __syncthreads();
        s[t] += x;
        __syncthreads();
    }
    if (t < n) data[t] = s[t] - v;
}

__global__ void add_base_kernel(int* __restrict__ off, const int* __restrict__ bsum,
                                int n, int* __restrict__ cursor) {
    int i = blockIdx.x * blockDim.x + threadIdx.x;
    if (i < n) {
        int o = off[i] + bsum[i >> 8];
        off[i] = o;
        cursor[i] = o;
    }
}

__global__ void scatter_kernel(const int* __restrict__ dst, int E,
                               int* __restrict__ cursor, int* __restrict__ csr) {
    int i = blockIdx.x * blockDim.x + threadIdx.x;
    if (i < E) {
        int p = atomicAdd(&cursor[dst[i]], 1);
        csr[p] = i;
    }
}

// ---------------- fused score + softmax + aggregate + ELU ----------------
// One wave (64 lanes) per destination node. Lane l owns floats [4l, 4l+4)
// of the 256-float row -> head = l/8; the 8-lane group covers one head's 32 dims.
__global__ void aggregate_kernel(const float* __restrict__ feat,
                                 const float* __restrict__ attn_r,
                                 const int* __restrict__ csr,
                                 const int* __restrict__ offsets,
                                 const int* __restrict__ count,
                                 float* __restrict__ out, int N) {
    int gtid = blockIdx.x * blockDim.x + threadIdx.x;
    int node = gtid >> 6;
    int lane = threadIdx.x & 63;
    if (node >= N) return;

    float4 ar = reinterpret_cast<const float4*>(attn_r)[lane];  // attn_r[head][...]
    int start = offsets[node];
    int len   = count[node];

    float4 acc = make_float4(0.f, 0.f, 0.f, 0.f);
    float  den = 0.f;

    for (int k = 0; k < len; ++k) {
        int e = csr[start + k];
        float4 f = reinterpret_cast<const float4*>(feat + (size_t)e * HD)[lane];
        float part = f.x * ar.x + f.y * ar.y + f.z * ar.z + f.w * ar.w;
        // reduce the 32-dim head dot across the 8 lanes of this head group
        part += __shfl_xor(part, 1);
        part += __shfl_xor(part, 2);
        part += __shfl_xor(part, 4);
        float er  = part;
        float el  = (er > 0.f) ? er : NEG_SLOPE * er;   // leaky relu
        float num = expf(el);                           // unnormalized softmax weight
        den   += num;
        acc.x += num * f.x;
        acc.y += num * f.y;
        acc.z += num * f.z;
        acc.w += num * f.w;
    }

    float inv = (len > 0) ? (1.0f / den) : 0.0f;  // zero-degree node -> out 0
    float4 o;
    o.x = acc.x * inv;
    o.y = acc.y * inv;
    o.z = acc.z * inv;
    o.w = acc.w * inv;
    // ELU
    o.x = (o.x > 0.f) ? o.x : expm1f(o.x);
    o.y = (o.y > 0.f) ? o.y : expm1f(o.y);
    o.z = (o.z > 0.f) ? o.z : expm1f(o.z);
    o.w = (o.w > 0.f) ? o.w : expm1f(o.w);
    reinterpret_cast<float4*>(out + (size_t)node * HD)[lane] = o;
}

// ---------------- launch ----------------

extern "C" void kernel_launch(void* const* d_in, const int* in_sizes, int n_in,
                              void* d_out, int out_size, void* d_ws, size_t ws_size,
                              hipStream_t stream) {
    const float* feat   = (const float*)d_in[0];
    const float* attn_r = (const float*)d_in[1];
    const int*   dst    = (const int*)d_in[2];
    float*       out    = (float*)d_out;

    const int E = in_sizes[0] / HD;   // 500000
    const int N = out_size / HD;      // 100000
    const int NB = (N + 255) / 256;   // scan blocks (391 <= 1024)

    // workspace layout (ints): count[N] | offsets[N] | cursor[N] | bsum[1024] | csr[E]
    int* count   = (int*)d_ws;
    int* offsets = count + N;
    int* cursor  = offsets + N;
    int* bsum    = cursor + N;
    int* csr     = bsum + 1024;
    // total = (3N + 1024 + E)*4 ~= 3.2 MB

    hipMemsetAsync(count, 0, (size_t)N * sizeof(int), stream);

    hist_kernel<<<(E + 255) / 256, 256, 0, stream>>>(dst, E, count);
    scan_block_kernel<<<NB, 256, 0, stream>>>(count, N, offsets, bsum);
    scan_single_kernel<<<1, 1024, 0, stream>>>(bsum, NB);
    add_base_kernel<<<NB, 256, 0, stream>>>(offsets, bsum, N, cursor);
    scatter_kernel<<<(E + 255) / 256, 256, 0, stream>>>(dst, E, cursor, csr);

    aggregate_kernel<<<(N + 3) / 4, 256, 0, stream>>>(feat, attn_r, csr, offsets, count, out, N);
}

// Round 2
// 191.872 us; speedup vs baseline: 1.1030x; 1.1030x over previous
//
#include <hip/hip_runtime.h>
#include <hip/hip_bf16.h>

#define H 8
#define D 32
#define HD 256            // H*D floats per edge/node row
#define NEG_SLOPE 0.01f

// ---------------- CSR build ----------------

__global__ void hist_kernel(const int* __restrict__ dst, int E, int* __restrict__ count) {
    int i = blockIdx.x * blockDim.x + threadIdx.x;
    if (i < E) atomicAdd(&count[dst[i]], 1);
}

// per-256-block exclusive scan; writes block totals
__global__ void scan_block_kernel(const int* __restrict__ in, int n,
                                  int* __restrict__ out_excl, int* __restrict__ bsum) {
    __shared__ int s[256];
    int t = threadIdx.x;
    int i = blockIdx.x * 256 + t;
    int v = (i < n) ? in[i] : 0;
    s[t] = v;
    __syncthreads();
    for (int off = 1; off < 256; off <<= 1) {
        int x = (t >= off) ? s[t - off] : 0;
        __syncthreads();
        s[t] += x;
        __syncthreads();
    }
    if (i < n) out_excl[i] = s[t] - v;            // exclusive
    if (t == 255) bsum[blockIdx.x] = s[255];      // block total
}

// single-block exclusive scan of up to 1024 block totals (NB = ceil(100k/256) = 391)
__global__ void scan_single_kernel(int* __restrict__ data, int n) {
    __shared__ int s[1024];
    int t = threadIdx.x;
    int v = (t < n) ? data[t] : 0;
    s[t] = v;
    __syncthreads();
    for (int off = 1; off < 1024; off <<= 1) {
        int x = (t >= off) ? s[t - off] : 0;
        __syncthreads();
        s[t] += x;
        __syncthreads();
    }
    if (t < n) data[t] = s[t] - v;
}

__global__ void add_base_kernel(int* __restrict__ off, const int* __restrict__ bsum,
                                int n, int* __restrict__ cursor) {
    int i = blockIdx.x * blockDim.x + threadIdx.x;
    if (i < n) {
        int o = off[i] + bsum[i >> 8];
        off[i] = o;
        cursor[i] = o;
    }
}

__global__ void scatter_kernel(const int* __restrict__ dst, int E,
                               int* __restrict__ cursor, int* __restrict__ csr) {
    int i = blockIdx.x * blockDim.x + threadIdx.x;
    if (i < E) {
        int p = atomicAdd(&cursor[dst[i]], 1);
        csr[p] = i;
    }
}

// ---------------- fused score + softmax + aggregate + ELU ----------------
// One wave (64 lanes) per destination node. Lane l owns floats [4l, 4l+4)
// of the 256-float row -> head = l/8; the 8-lane group covers one head's 32 dims.
//
// Latency strategy:
//  - all edge indices for the node are fetched with ONE coalesced vector load
//    (csr[start+lane]); per-edge index comes from __shfl (no serial uniform loads)
//  - feat rows are prefetched with a depth-2 rotating register pipeline so two
//    1 KB HBM loads are in flight per wave at all times
__global__ void aggregate_kernel(const float* __restrict__ feat,
                                 const float* __restrict__ attn_r,
                                 const int* __restrict__ csr,
                                 const int* __restrict__ offsets,
                                 const int* __restrict__ count,
                                 float* __restrict__ out, int N) {
    int gtid = blockIdx.x * blockDim.x + threadIdx.x;
    int node = gtid >> 6;
    int lane = threadIdx.x & 63;
    if (node >= N) return;

    float4 ar = reinterpret_cast<const float4*>(attn_r)[lane];  // attn_r[head][...]
    int start = offsets[node];
    int len   = count[node];

    float4 acc = make_float4(0.f, 0.f, 0.f, 0.f);
    float  den = 0.f;

    for (int base = 0; base < len; base += 64) {
        int rem = min(64, len - base);
        // one coalesced load grabs up to 64 edge indices for this node
        int iclamp = min(lane, rem - 1);
        int eidx   = csr[start + base + iclamp];

        // depth-2 rotating prefetch of feat rows
        int e0 = __shfl(eidx, 0);
        float4 f0 = reinterpret_cast<const float4*>(feat + (size_t)e0 * HD)[lane];
        float4 f1 = f0;
        if (rem > 1) {
            int e1 = __shfl(eidx, 1);
            f1 = reinterpret_cast<const float4*>(feat + (size_t)e1 * HD)[lane];
        }

        for (int k = 0; k < rem; ++k) {
            float4 f = f0;
            f0 = f1;
            int kn = k + 2;
            if (kn < rem) {
                int en = __shfl(eidx, kn);
                f1 = reinterpret_cast<const float4*>(feat + (size_t)en * HD)[lane];
            }
            float part = f.x * ar.x + f.y * ar.y + f.z * ar.z + f.w * ar.w;
            // reduce the 32-dim head dot across the 8 lanes of this head group
            part += __shfl_xor(part, 1);
            part += __shfl_xor(part, 2);
            part += __shfl_xor(part, 4);
            float er  = part;
            float el  = (er > 0.f) ? er : NEG_SLOPE * er;   // leaky relu
            float num = __expf(el);                         // unnormalized softmax weight
            den   += num;
            acc.x += num * f.x;
            acc.y += num * f.y;
            acc.z += num * f.z;
            acc.w += num * f.w;
        }
    }

    float inv = (len > 0) ? (1.0f / den) : 0.0f;  // zero-degree node -> out 0
    float4 o;
    o.x = acc.x * inv;
    o.y = acc.y * inv;
    o.z = acc.z * inv;
    o.w = acc.w * inv;
    // ELU
    o.x = (o.x > 0.f) ? o.x : expm1f(o.x);
    o.y = (o.y > 0.f) ? o.y : expm1f(o.y);
    o.z = (o.z > 0.f) ? o.z : expm1f(o.z);
    o.w = (o.w > 0.f) ? o.w : expm1f(o.w);
    reinterpret_cast<float4*>(out + (size_t)node * HD)[lane] = o;
}

// ---------------- launch ----------------

extern "C" void kernel_launch(void* const* d_in, const int* in_sizes, int n_in,
                              void* d_out, int out_size, void* d_ws, size_t ws_size,
                              hipStream_t stream) {
    const float* feat   = (const float*)d_in[0];
    const float* attn_r = (const float*)d_in[1];
    const int*   dst    = (const int*)d_in[2];
    float*       out    = (float*)d_out;

    const int E = in_sizes[0] / HD;   // 500000
    const int N = out_size / HD;      // 100000
    const int NB = (N + 255) / 256;   // scan blocks (391 <= 1024)

    // workspace layout (ints): count[N] | offsets[N] | cursor[N] | bsum[1024] | csr[E]
    int* count   = (int*)d_ws;
    int* offsets = count + N;
    int* cursor  = offsets + N;
    int* bsum    = cursor + N;
    int* csr     = bsum + 1024;
    // total = (3N + 1024 + E)*4 ~= 3.2 MB

    hipMemsetAsync(count, 0, (size_t)N * sizeof(int), stream);

    hist_kernel<<<(E + 255) / 256, 256, 0, stream>>>(dst, E, count);
    scan_block_kernel<<<NB, 256, 0, stream>>>(count, N, offsets, bsum);
    scan_single_kernel<<<1, 1024, 0, stream>>>(bsum, NB);
    add_base_kernel<<<NB, 256, 0, stream>>>(offsets, bsum, N, cursor);
    scatter_kernel<<<(E + 255) / 256, 256, 0, stream>>>(dst, E, cursor, csr);

    aggregate_kernel<<<(N + 3) / 4, 256, 0, stream>>>(feat, attn_r, csr, offsets, count, out, N);
}

// Round 4
// 175.626 us; speedup vs baseline: 1.2051x; 1.0925x over previous
//
#include <hip/hip_runtime.h>
#include <hip/hip_bf16.h>

#define H 8
#define D 32
#define HD 256            // H*D floats per edge/node row
#define NEG_SLOPE 0.01f

typedef float f32x4 __attribute__((ext_vector_type(4)));

// ---------------- CSR build ----------------

__global__ void hist_kernel(const int* __restrict__ dst, int E, int* __restrict__ count) {
    int i = blockIdx.x * blockDim.x + threadIdx.x;
    int base = i * 4;
    if (base + 3 < E) {
        int4 d = *reinterpret_cast<const int4*>(dst + base);
        atomicAdd(&count[d.x], 1);
        atomicAdd(&count[d.y], 1);
        atomicAdd(&count[d.z], 1);
        atomicAdd(&count[d.w], 1);
    } else {
        for (int k = base; k < E; ++k) atomicAdd(&count[dst[k]], 1);
    }
}

// per-256-block exclusive scan; writes block totals
__global__ void scan_block_kernel(const int* __restrict__ in, int n,
                                  int* __restrict__ out_excl, int* __restrict__ bsum) {
    __shared__ int s[256];
    int t = threadIdx.x;
    int i = blockIdx.x * 256 + t;
    int v = (i < n) ? in[i] : 0;
    s[t] = v;
    __syncthreads();
    for (int off = 1; off < 256; off <<= 1) {
        int x = (t >= off) ? s[t - off] : 0;
        __syncthreads();
        s[t] += x;
        __syncthreads();
    }
    if (i < n) out_excl[i] = s[t] - v;            // exclusive
    if (t == 255) bsum[blockIdx.x] = s[255];      // block total
}

// single-block exclusive scan of up to 1024 block totals (NB = ceil(100k/256) = 391)
__global__ void scan_single_kernel(int* __restrict__ data, int n) {
    __shared__ int s[1024];
    int t = threadIdx.x;
    int v = (t < n) ? data[t] : 0;
    s[t] = v;
    __syncthreads();
    for (int off = 1; off < 1024; off <<= 1) {
        int x = (t >= off) ? s[t - off] : 0;
        __syncthreads();
        s[t] += x;
        __syncthreads();
    }
    if (t < n) data[t] = s[t] - v;
}

__global__ void add_base_kernel(int* __restrict__ off, const int* __restrict__ bsum,
                                int n, int* __restrict__ cursor) {
    int i = blockIdx.x * blockDim.x + threadIdx.x;
    if (i < n) {
        int o = off[i] + bsum[i >> 8];
        off[i] = o;
        cursor[i] = o;
    }
}

__global__ void scatter_kernel(const int* __restrict__ dst, int E,
                               int* __restrict__ cursor, int* __restrict__ csr) {
    int i = blockIdx.x * blockDim.x + threadIdx.x;
    int base = i * 4;
    if (base + 3 < E) {
        int4 d = *reinterpret_cast<const int4*>(dst + base);
        int p0 = atomicAdd(&cursor[d.x], 1); csr[p0] = base;
        int p1 = atomicAdd(&cursor[d.y], 1); csr[p1] = base + 1;
        int p2 = atomicAdd(&cursor[d.z], 1); csr[p2] = base + 2;
        int p3 = atomicAdd(&cursor[d.w], 1); csr[p3] = base + 3;
    } else {
        for (int k = base; k < E; ++k) {
            int p = atomicAdd(&cursor[dst[k]], 1);
            csr[p] = k;
        }
    }
}

// ---------------- fused score + softmax + aggregate + ELU ----------------
// One wave (64 lanes) per destination node. Lane l owns floats [4l, 4l+4)
// of the 256-float row -> head = l/8; the 8-lane group covers one head's 32 dims.
//
// Latency strategy:
//  - all edge indices for the node via ONE coalesced load (csr[start+lane]),
//    per-edge index from __shfl
//  - depth-4 rotating register prefetch: up to 4 KB of feat rows in flight/wave
//  - nontemporal feat loads / out stores (each row touched exactly once)
__global__ void aggregate_kernel(const float* __restrict__ feat,
                                 const float* __restrict__ attn_r,
                                 const int* __restrict__ csr,
                                 const int* __restrict__ offsets,
                                 const int* __restrict__ count,
                                 float* __restrict__ out, int N) {
    int gtid = blockIdx.x * blockDim.x + threadIdx.x;
    int node = gtid >> 6;
    int lane = threadIdx.x & 63;
    if (node >= N) return;

    f32x4 ar = reinterpret_cast<const f32x4*>(attn_r)[lane];  // attn_r[head][...]
    int start = offsets[node];
    int len   = count[node];

    f32x4 acc = (f32x4)(0.f);
    float den = 0.f;

    const f32x4* featv = reinterpret_cast<const f32x4*>(feat);

    for (int base = 0; base < len; base += 64) {
        int rem = min(64, len - base);
        // one coalesced load grabs up to 64 edge indices for this node
        int iclamp = min(lane, rem - 1);
        int eidx   = csr[start + base + iclamp];

        // depth-4 rotating prefetch of feat rows
        int e0 = __shfl(eidx, 0);
        f32x4 f0 = __builtin_nontemporal_load(&featv[(size_t)e0 * 64 + lane]);
        f32x4 f1 = f0, f2 = f0, f3 = f0;
        if (rem > 1) { int e = __shfl(eidx, 1); f1 = __builtin_nontemporal_load(&featv[(size_t)e * 64 + lane]); }
        if (rem > 2) { int e = __shfl(eidx, 2); f2 = __builtin_nontemporal_load(&featv[(size_t)e * 64 + lane]); }
        if (rem > 3) { int e = __shfl(eidx, 3); f3 = __builtin_nontemporal_load(&featv[(size_t)e * 64 + lane]); }

        for (int k = 0; k < rem; ++k) {
            f32x4 f = f0;
            f0 = f1; f1 = f2; f2 = f3;
            int kn = k + 4;
            if (kn < rem) {
                int en = __shfl(eidx, kn);
                f3 = __builtin_nontemporal_load(&featv[(size_t)en * 64 + lane]);
            }
            float part = f.x * ar.x + f.y * ar.y + f.z * ar.z + f.w * ar.w;
            // reduce the 32-dim head dot across the 8 lanes of this head group
            part += __shfl_xor(part, 1);
            part += __shfl_xor(part, 2);
            part += __shfl_xor(part, 4);
            float er  = part;
            float el  = (er > 0.f) ? er : NEG_SLOPE * er;   // leaky relu
            float num = __expf(el);                         // unnormalized softmax weight
            den   += num;
            acc.x += num * f.x;
            acc.y += num * f.y;
            acc.z += num * f.z;
            acc.w += num * f.w;
        }
    }

    float inv = (len > 0) ? (1.0f / den) : 0.0f;  // zero-degree node -> out 0
    f32x4 o;
    o.x = acc.x * inv;
    o.y = acc.y * inv;
    o.z = acc.z * inv;
    o.w = acc.w * inv;
    // ELU
    o.x = (o.x > 0.f) ? o.x : expm1f(o.x);
    o.y = (o.y > 0.f) ? o.y : expm1f(o.y);
    o.z = (o.z > 0.f) ? o.z : expm1f(o.z);
    o.w = (o.w > 0.f) ? o.w : expm1f(o.w);
    __builtin_nontemporal_store(o, &reinterpret_cast<f32x4*>(out)[(size_t)node * 64 + lane]);
}

// ---------------- launch ----------------

extern "C" void kernel_launch(void* const* d_in, const int* in_sizes, int n_in,
                              void* d_out, int out_size, void* d_ws, size_t ws_size,
                              hipStream_t stream) {
    const float* feat   = (const float*)d_in[0];
    const float* attn_r = (const float*)d_in[1];
    const int*   dst    = (const int*)d_in[2];
    float*       out    = (float*)d_out;

    const int E = in_sizes[0] / HD;   // 500000
    const int N = out_size / HD;      // 100000
    const int NB = (N + 255) / 256;   // scan blocks (391 <= 1024)

    // workspace layout (ints): count[N] | offsets[N] | cursor[N] | bsum[1024] | csr[E]
    int* count   = (int*)d_ws;
    int* offsets = count + N;
    int* cursor  = offsets + N;
    int* bsum    = cursor + N;
    int* csr     = bsum + 1024;
    // total = (3N + 1024 + E)*4 ~= 3.2 MB

    (void)hipMemsetAsync(count, 0, (size_t)N * sizeof(int), stream);

    const int E4 = (E + 3) / 4;
    hist_kernel<<<(E4 + 255) / 256, 256, 0, stream>>>(dst, E, count);
    scan_block_kernel<<<NB, 256, 0, stream>>>(count, N, offsets, bsum);
    scan_single_kernel<<<1, 1024, 0, stream>>>(bsum, NB);
    add_base_kernel<<<NB, 256, 0, stream>>>(offsets, bsum, N, cursor);
    scatter_kernel<<<(E4 + 255) / 256, 256, 0, stream>>>(dst, E, cursor, csr);

    aggregate_kernel<<<(N + 3) / 4, 256, 0, stream>>>(feat, attn_r, csr, offsets, count, out, N);
}

// Round 5
// 170.335 us; speedup vs baseline: 1.2425x; 1.0311x over previous
//
#include <hip/hip_runtime.h>
#include <hip/hip_bf16.h>

#define H 8
#define D 32
#define HD 256            // H*D floats per edge/node row
#define NEG_SLOPE 0.01f

typedef float f32x4 __attribute__((ext_vector_type(4)));

// ---------------- CSR build ----------------

__global__ void hist_kernel(const int* __restrict__ dst, int E, int* __restrict__ count) {
    int i = blockIdx.x * blockDim.x + threadIdx.x;
    int base = i * 4;
    if (base + 3 < E) {
        int4 d = *reinterpret_cast<const int4*>(dst + base);
        atomicAdd(&count[d.x], 1);
        atomicAdd(&count[d.y], 1);
        atomicAdd(&count[d.z], 1);
        atomicAdd(&count[d.w], 1);
    } else {
        for (int k = base; k < E; ++k) atomicAdd(&count[dst[k]], 1);
    }
}

// per-256-block exclusive scan; writes block totals
__global__ void scan_block_kernel(const int* __restrict__ in, int n,
                                  int* __restrict__ out_excl, int* __restrict__ bsum) {
    __shared__ int s[256];
    int t = threadIdx.x;
    int i = blockIdx.x * 256 + t;
    int v = (i < n) ? in[i] : 0;
    s[t] = v;
    __syncthreads();
    for (int off = 1; off < 256; off <<= 1) {
        int x = (t >= off) ? s[t - off] : 0;
        __syncthreads();
        s[t] += x;
        __syncthreads();
    }
    if (i < n) out_excl[i] = s[t] - v;            // exclusive
    if (t == 255) bsum[blockIdx.x] = s[255];      // block total
}

// add scanned block bases (each block redundantly scans bsum[0..nb) in LDS),
// and emit packed CSR row descriptors pack[i] = (start, len) + cursor init.
__global__ void add_base_kernel(const int* __restrict__ off_excl,
                                const int* __restrict__ count,
                                const int* __restrict__ bsum, int nb, int n,
                                int2* __restrict__ pack, int* __restrict__ cursor) {
    __shared__ int s[512];
    int t = threadIdx.x;
    // load block sums (nb <= 512)
    s[t] = (t < nb) ? bsum[t] : 0;
    s[t + 256] = (t + 256 < nb) ? bsum[t + 256] : 0;
    __syncthreads();
    // inclusive scan over 512
    for (int off = 1; off < 512; off <<= 1) {
        int x0 = (t >= off) ? s[t - off] : 0;
        int x1 = (t + 256 >= off) ? s[t + 256 - off] : 0;
        __syncthreads();
        s[t] += x0;
        s[t + 256] += x1;
        __syncthreads();
    }
    int b = blockIdx.x;
    int base = (b > 0) ? s[b - 1] : 0;   // exclusive prefix of this block
    int i = b * 256 + t;
    if (i < n) {
        int o = off_excl[i] + base;
        pack[i] = make_int2(o, count[i]);
        cursor[i] = o;
    }
}

__global__ void scatter_kernel(const int* __restrict__ dst, int E,
                               int* __restrict__ cursor, int* __restrict__ csr) {
    int i = blockIdx.x * blockDim.x + threadIdx.x;
    int base = i * 4;
    if (base + 3 < E) {
        int4 d = *reinterpret_cast<const int4*>(dst + base);
        int p0 = atomicAdd(&cursor[d.x], 1); csr[p0] = base;
        int p1 = atomicAdd(&cursor[d.y], 1); csr[p1] = base + 1;
        int p2 = atomicAdd(&cursor[d.z], 1); csr[p2] = base + 2;
        int p3 = atomicAdd(&cursor[d.w], 1); csr[p3] = base + 3;
    } else {
        for (int k = base; k < E; ++k) {
            int p = atomicAdd(&cursor[dst[k]], 1);
            csr[p] = k;
        }
    }
}

// ---------------- fused score + softmax + aggregate + ELU ----------------
// One wave (64 lanes) per destination node. Lane l owns floats [4l, 4l+4)
// of the 256-float row -> head = l/8; the 8-lane group covers one head's 32 dims.
//
// Latency strategy:
//  - (start,len) packed as one int2 load (single L2 round trip to start chain)
//  - all edge indices via ONE coalesced load (csr[start+lane]), shfl-broadcast
//  - static depth-8 batches: issue 8 row loads into named registers, then
//    process 8 -> zero register-rotation moves, 8 KB in flight per wave
//  - nontemporal feat loads / out stores (each row touched exactly once)
__global__ void aggregate_kernel(const float* __restrict__ feat,
                                 const float* __restrict__ attn_r,
                                 const int* __restrict__ csr,
                                 const int2* __restrict__ pack,
                                 float* __restrict__ out, int N) {
    int gtid = blockIdx.x * blockDim.x + threadIdx.x;
    int node = gtid >> 6;
    int lane = threadIdx.x & 63;
    if (node >= N) return;

    f32x4 ar = reinterpret_cast<const f32x4*>(attn_r)[lane];  // attn_r[head][...]
    int2 se  = pack[node];
    int start = se.x;
    int len   = se.y;

    f32x4 acc = (f32x4)(0.f);
    float den = 0.f;

    const f32x4* featv = reinterpret_cast<const f32x4*>(feat);

#define LOADF(i, fi) if (r > (i)) { int e = __shfl(eidx, c + (i)); \
    fi = __builtin_nontemporal_load(&featv[(size_t)e * 64 + lane]); }
#define PROC(fi) { \
    float part = fi.x * ar.x + fi.y * ar.y + fi.z * ar.z + fi.w * ar.w; \
    part += __shfl_xor(part, 1); \
    part += __shfl_xor(part, 2); \
    part += __shfl_xor(part, 4); \
    float el  = (part > 0.f) ? part : NEG_SLOPE * part; \
    float num = __expf(el); \
    den   += num; \
    acc.x += num * fi.x; acc.y += num * fi.y; \
    acc.z += num * fi.z; acc.w += num * fi.w; }

    for (int base = 0; base < len; base += 64) {
        int rem = min(64, len - base);
        // one coalesced load grabs up to 64 edge indices for this node
        int eidx = csr[start + base + min(lane, rem - 1)];

        for (int c = 0; c < rem; c += 8) {
            int r = rem - c;          // wave-uniform
            f32x4 f0, f1, f2, f3, f4, f5, f6, f7;
            { int e = __shfl(eidx, c); f0 = __builtin_nontemporal_load(&featv[(size_t)e * 64 + lane]); }
            LOADF(1, f1) LOADF(2, f2) LOADF(3, f3)
            LOADF(4, f4) LOADF(5, f5) LOADF(6, f6) LOADF(7, f7)
            PROC(f0)
            if (r > 1) PROC(f1)
            if (r > 2) PROC(f2)
            if (r > 3) PROC(f3)
            if (r > 4) PROC(f4)
            if (r > 5) PROC(f5)
            if (r > 6) PROC(f6)
            if (r > 7) PROC(f7)
        }
    }
#undef LOADF
#undef PROC

    float inv = (len > 0) ? (1.0f / den) : 0.0f;  // zero-degree node -> out 0
    f32x4 o;
    o.x = acc.x * inv;
    o.y = acc.y * inv;
    o.z = acc.z * inv;
    o.w = acc.w * inv;
    // ELU
    o.x = (o.x > 0.f) ? o.x : expm1f(o.x);
    o.y = (o.y > 0.f) ? o.y : expm1f(o.y);
    o.z = (o.z > 0.f) ? o.z : expm1f(o.z);
    o.w = (o.w > 0.f) ? o.w : expm1f(o.w);
    __builtin_nontemporal_store(o, &reinterpret_cast<f32x4*>(out)[(size_t)node * 64 + lane]);
}

// ---------------- launch ----------------

extern "C" void kernel_launch(void* const* d_in, const int* in_sizes, int n_in,
                              void* d_out, int out_size, void* d_ws, size_t ws_size,
                              hipStream_t stream) {
    const float* feat   = (const float*)d_in[0];
    const float* attn_r = (const float*)d_in[1];
    const int*   dst    = (const int*)d_in[2];
    float*       out    = (float*)d_out;

    const int E = in_sizes[0] / HD;   // 500000
    const int N = out_size / HD;      // 100000
    const int NB = (N + 255) / 256;   // scan blocks (391 <= 512)

    // workspace layout (ints): count[N] | off_excl[N] | cursor[N] | bsum[512] | pack[2N] | csr[E]
    int*  count    = (int*)d_ws;
    int*  off_excl = count + N;
    int*  cursor   = off_excl + N;
    int*  bsum     = cursor + N;
    int2* pack     = (int2*)(bsum + 512);
    int*  csr      = (int*)(pack + N);
    // total = (5N + 512 + E)*4 ~= 4.0 MB

    (void)hipMemsetAsync(count, 0, (size_t)N * sizeof(int), stream);

    const int E4 = (E + 3) / 4;
    hist_kernel<<<(E4 + 255) / 256, 256, 0, stream>>>(dst, E, count);
    scan_block_kernel<<<NB, 256, 0, stream>>>(count, N, off_excl, bsum);
    add_base_kernel<<<NB, 256, 0, stream>>>(off_excl, count, bsum, NB, N, pack, cursor);
    scatter_kernel<<<(E4 + 255) / 256, 256, 0, stream>>>(dst, E, cursor, csr);

    aggregate_kernel<<<(N + 3) / 4, 256, 0, stream>>>(feat, attn_r, csr, pack, out, N);
}